// Round 6
// baseline (431.905 us; speedup 1.0000x reference)
//
#include <hip/hip_runtime.h>
#include <hip/hip_bf16.h>

// KGAT via on-device CSR (no float atomics):
//   k1 hdot:  hdot[n] = emb[n].att_w[0:64];  rb[r] = rel[r].att_w[64:128] + b
//   k2 hist:  cnt[head]++                      (int atomics)
//   k3 scan:  off = exclusive_scan(cnt)  (+ bucket offsets boff/bcur, off[N]=E)
//   k4 scatter1: bin edges by head>>6 (3125 buckets, L2-resident write frontier)
//      packed 4B: (head&63)<<19 | rel<<18 | tail
//   k5 scatter2: block per bucket, LDS cursors -> exact CSR slot (contiguous window)
//   k6 aggr:  per-head segment-sum; score recomputed (2 sigmoids/head + select)
//   k7 xform: out = tanh(aggr @ W^T + b), 16 lanes/row, ILP=4, grid-stride

#define DIM 64
#define TMASK 0x3FFFF
#define RBIT (1 << 18)

// ---------------- k1: per-entity attention dot ----------------
__global__ __launch_bounds__(256) void kgat_hdot(
    const float* __restrict__ emb, const float* __restrict__ rel,
    const float* __restrict__ att_w, const float* __restrict__ att_b,
    float* __restrict__ hdot, float* __restrict__ rb,
    int n_ent, int n_rel) {
  int gid = blockIdx.x * 256 + threadIdx.x;
  int n = gid >> 4;
  int q = threadIdx.x & 15;
  if (n >= n_ent + n_rel) return;
  float4 v, w;
  if (n < n_ent) {
    v = ((const float4*)emb)[n * 16 + q];
    w = ((const float4*)att_w)[q];
  } else {
    v = ((const float4*)rel)[(n - n_ent) * 16 + q];
    w = ((const float4*)att_w)[16 + q];
  }
  float p = v.x * w.x + v.y * w.y + v.z * w.z + v.w * w.w;
  p += __shfl_xor(p, 1);
  p += __shfl_xor(p, 2);
  p += __shfl_xor(p, 4);
  p += __shfl_xor(p, 8);
  if (q == 0) {
    if (n < n_ent) hdot[n] = p;
    else rb[n - n_ent] = p + att_b[0];
  }
}

// ---------------- k2: histogram of head degrees ----------------
__global__ __launch_bounds__(256) void kgat_hist(
    const int* __restrict__ ei, int* __restrict__ cnt, int E) {
  int e = blockIdx.x * 256 + threadIdx.x;
  if (e < E) atomicAdd(&cnt[ei[e]], 1);
}

// ---------------- k3: exclusive scan (1024 elems / block) ----------------
__global__ __launch_bounds__(256) void scan_a(
    const int* __restrict__ cnt, int* __restrict__ incl,
    int* __restrict__ partial, int n) {
  __shared__ int s[256];
  int base = blockIdx.x * 1024 + threadIdx.x * 4;
  int v0 = 0, v1 = 0, v2 = 0, v3 = 0;
  if (base + 0 < n) v0 = cnt[base + 0];
  if (base + 1 < n) v1 = cnt[base + 1];
  if (base + 2 < n) v2 = cnt[base + 2];
  if (base + 3 < n) v3 = cnt[base + 3];
  int tsum = v0 + v1 + v2 + v3;
  s[threadIdx.x] = tsum;
  __syncthreads();
  for (int d = 1; d < 256; d <<= 1) {
    int val = (threadIdx.x >= (unsigned)d) ? s[threadIdx.x - d] : 0;
    __syncthreads();
    s[threadIdx.x] += val;
    __syncthreads();
  }
  int texcl = s[threadIdx.x] - tsum;
  if (base + 0 < n) incl[base + 0] = texcl + v0;
  if (base + 1 < n) incl[base + 1] = texcl + v0 + v1;
  if (base + 2 < n) incl[base + 2] = texcl + v0 + v1 + v2;
  if (base + 3 < n) incl[base + 3] = texcl + tsum;
  if (threadIdx.x == 255) partial[blockIdx.x] = s[255];
}

__global__ __launch_bounds__(256) void scan_b(int* __restrict__ partial, int nb) {
  __shared__ int s[256];
  int v = (threadIdx.x < (unsigned)nb) ? partial[threadIdx.x] : 0;
  s[threadIdx.x] = v;
  __syncthreads();
  for (int d = 1; d < 256; d <<= 1) {
    int val = (threadIdx.x >= (unsigned)d) ? s[threadIdx.x - d] : 0;
    __syncthreads();
    s[threadIdx.x] += val;
    __syncthreads();
  }
  if (threadIdx.x < (unsigned)nb) partial[threadIdx.x] = s[threadIdx.x] - v;
}

__global__ __launch_bounds__(256) void scan_c(
    const int* __restrict__ incl, const int* __restrict__ cnt,
    const int* __restrict__ partial, int* __restrict__ off,
    int* __restrict__ boff, int* __restrict__ bcur, int n) {
  int i = blockIdx.x * 256 + threadIdx.x;
  if (i >= n) return;
  int c = cnt[i];
  int o = incl[i] - c + partial[i >> 10];
  off[i] = o;
  if ((i & 63) == 0) {
    boff[i >> 6] = o;
    bcur[i >> 6] = o;
  }
  if (i == n - 1) {
    off[n] = o + c;                 // = E
    boff[((n + 63) >> 6)] = o + c;  // sentinel bucket end
  }
}

// ---------------- k4: stage-1 binned scatter (bucket = head>>6) ----------------
__global__ __launch_bounds__(256) void kgat_scatter1(
    const int* __restrict__ ei, const int* __restrict__ et,
    int* __restrict__ bcur, int* __restrict__ stage, int E) {
  int e = blockIdx.x * 256 + threadIdx.x;
  if (e >= E) return;
  int h = ei[e];
  int t = ei[E + e];
  int r = et[e];
  int pos = atomicAdd(&bcur[h >> 6], 1);
  stage[pos] = ((h & 63) << 19) | (r << 18) | t;
}

// ---------------- k5: stage-2 in-bucket placement (block per bucket) ----------------
__global__ __launch_bounds__(256) void kgat_scatter2(
    const int* __restrict__ stage, const int* __restrict__ off,
    const int* __restrict__ boff, int* __restrict__ payload, int n) {
  __shared__ int lcur[64];
  int b = blockIdx.x;
  int s0 = boff[b], s1 = boff[b + 1];
  if (threadIdx.x < 64) {
    int hidx = (b << 6) + threadIdx.x;
    lcur[threadIdx.x] = off[hidx < n ? hidx : n];
  }
  __syncthreads();
  for (int p = s0 + threadIdx.x; p < s1; p += 256) {
    int v = stage[p];
    int hl = (v >> 19) & 63;
    int pos = atomicAdd(&lcur[hl], 1);
    payload[pos] = v;
  }
}

// ---------------- k6: segment-sum, x4 unrolled gathers, score on the fly ----------------
__global__ __launch_bounds__(256) void kgat_aggr(
    const int* __restrict__ off, const int* __restrict__ payload,
    const float* __restrict__ emb, const float* __restrict__ hdot,
    const float* __restrict__ rb, float* __restrict__ out, int n) {
  int gid = blockIdx.x * 256 + threadIdx.x;
  int h = gid >> 4;
  int q = threadIdx.x & 15;
  if (h >= n) return;
  int p = off[h];
  int p1 = off[h + 1];
  float hd = hdot[h];
  float sc0 = 1.0f / (1.0f + __expf(-(hd + rb[0])));
  float sc1 = 1.0f / (1.0f + __expf(-(hd + rb[1])));
  float4 acc = make_float4(0.f, 0.f, 0.f, 0.f);
  const float4* emb4 = (const float4*)emb;
  for (; p + 4 <= p1; p += 4) {
    int v0 = payload[p + 0];
    int v1 = payload[p + 1];
    int v2 = payload[p + 2];
    int v3 = payload[p + 3];
    float4 t0 = emb4[(v0 & TMASK) * 16 + q];
    float4 t1 = emb4[(v1 & TMASK) * 16 + q];
    float4 t2 = emb4[(v2 & TMASK) * 16 + q];
    float4 t3 = emb4[(v3 & TMASK) * 16 + q];
    float s0 = (v0 & RBIT) ? sc1 : sc0;
    float s1 = (v1 & RBIT) ? sc1 : sc0;
    float s2 = (v2 & RBIT) ? sc1 : sc0;
    float s3 = (v3 & RBIT) ? sc1 : sc0;
    acc.x = fmaf(s0, t0.x, acc.x); acc.y = fmaf(s0, t0.y, acc.y);
    acc.z = fmaf(s0, t0.z, acc.z); acc.w = fmaf(s0, t0.w, acc.w);
    acc.x = fmaf(s1, t1.x, acc.x); acc.y = fmaf(s1, t1.y, acc.y);
    acc.z = fmaf(s1, t1.z, acc.z); acc.w = fmaf(s1, t1.w, acc.w);
    acc.x = fmaf(s2, t2.x, acc.x); acc.y = fmaf(s2, t2.y, acc.y);
    acc.z = fmaf(s2, t2.z, acc.z); acc.w = fmaf(s2, t2.w, acc.w);
    acc.x = fmaf(s3, t3.x, acc.x); acc.y = fmaf(s3, t3.y, acc.y);
    acc.z = fmaf(s3, t3.z, acc.z); acc.w = fmaf(s3, t3.w, acc.w);
  }
  for (; p < p1; ++p) {
    int v0 = payload[p];
    float s0 = (v0 & RBIT) ? sc1 : sc0;
    float4 t0 = emb4[(v0 & TMASK) * 16 + q];
    acc.x = fmaf(s0, t0.x, acc.x); acc.y = fmaf(s0, t0.y, acc.y);
    acc.z = fmaf(s0, t0.z, acc.z); acc.w = fmaf(s0, t0.w, acc.w);
  }
  ((float4*)out)[h * 16 + q] = acc;
}

// ---------------- k7: out = tanh(out @ W^T + b), 16 lanes/row, grid-stride ----------------
__global__ __launch_bounds__(256) void kgat_transform(
    float* __restrict__ out, const float* __restrict__ Ww,
    const float* __restrict__ Wb, int nrows) {
  __shared__ float Ws[64][68];  // Ws[i][j] = Ww[j][i]; stride 68 -> 16B-aligned rows
  for (int idx = threadIdx.x; idx < 64 * 64; idx += 256) {
    int j = idx >> 6, i = idx & 63;
    Ws[i][j] = Ww[idx];
  }
  __syncthreads();
  int q = threadIdx.x & 15;
  int grp = threadIdx.x >> 4;
  int lanebase = (threadIdx.x & 63) & ~15;
  int stride = gridDim.x * 16;
  float4 bb = ((const float4*)Wb)[q];
  for (int h = blockIdx.x * 16 + grp; h < nrows; h += stride) {
    float4 a = ((const float4*)out)[h * 16 + q];
    float4 o = bb;
#pragma unroll 4
    for (int j = 0; j < 16; ++j) {
      float a0 = __shfl(a.x, lanebase + j);
      float a1 = __shfl(a.y, lanebase + j);
      float a2 = __shfl(a.z, lanebase + j);
      float a3 = __shfl(a.w, lanebase + j);
      float4 w0 = *(const float4*)&Ws[4 * j + 0][4 * q];
      float4 w1 = *(const float4*)&Ws[4 * j + 1][4 * q];
      float4 w2 = *(const float4*)&Ws[4 * j + 2][4 * q];
      float4 w3 = *(const float4*)&Ws[4 * j + 3][4 * q];
      o.x = fmaf(a0, w0.x, o.x); o.y = fmaf(a0, w0.y, o.y);
      o.z = fmaf(a0, w0.z, o.z); o.w = fmaf(a0, w0.w, o.w);
      o.x = fmaf(a1, w1.x, o.x); o.y = fmaf(a1, w1.y, o.y);
      o.z = fmaf(a1, w1.z, o.z); o.w = fmaf(a1, w1.w, o.w);
      o.x = fmaf(a2, w2.x, o.x); o.y = fmaf(a2, w2.y, o.y);
      o.z = fmaf(a2, w2.z, o.z); o.w = fmaf(a2, w2.w, o.w);
      o.x = fmaf(a3, w3.x, o.x); o.y = fmaf(a3, w3.y, o.y);
      o.z = fmaf(a3, w3.z, o.z); o.w = fmaf(a3, w3.w, o.w);
    }
    o.x = tanhf(o.x); o.y = tanhf(o.y); o.z = tanhf(o.z); o.w = tanhf(o.w);
    ((float4*)out)[h * 16 + q] = o;
  }
}

extern "C" void kernel_launch(void* const* d_in, const int* in_sizes, int n_in,
                              void* d_out, int out_size, void* d_ws, size_t ws_size,
                              hipStream_t stream) {
  const int* edge_index = (const int*)d_in[0];
  const int* edge_type  = (const int*)d_in[1];
  const float* entity_emb   = (const float*)d_in[2];
  const float* relation_emb = (const float*)d_in[3];
  const float* att_w = (const float*)d_in[4];
  const float* att_b = (const float*)d_in[5];
  const float* W_w   = (const float*)d_in[6];
  const float* W_b   = (const float*)d_in[7];
  float* out = (float*)d_out;

  const int E     = in_sizes[0] / 2;
  const int N_ENT = in_sizes[2] / DIM;
  const int N_REL = in_sizes[3] / DIM;
  const int NB    = (N_ENT + 63) >> 6;  // head buckets

  // ws layout (4B units)
  int* w32 = (int*)d_ws;
  float* hdot   = (float*)w32;                 // N_ENT
  float* rb     = (float*)(w32 + N_ENT);       // 8
  int*   cnt    = w32 + N_ENT + 8;             // N_ENT
  int*   off    = cnt + N_ENT;                 // N_ENT + 1
  int*   boff   = off + N_ENT + 1;             // NB + 1
  int*   bcur   = boff + NB + 1;               // NB
  int*   partial= bcur + NB;                   // 256
  int*   stage  = partial + 256;               // E
  int*   payload= stage + E;                   // E

  hipMemsetAsync(cnt, 0, (size_t)N_ENT * sizeof(int), stream);

  {
    int blocks = ((N_ENT + N_REL) * 16 + 255) / 256;
    kgat_hdot<<<blocks, 256, 0, stream>>>(entity_emb, relation_emb, att_w, att_b,
                                          hdot, rb, N_ENT, N_REL);
  }
  kgat_hist<<<(E + 255) / 256, 256, 0, stream>>>(edge_index, cnt, E);
  {
    int nb = (N_ENT + 1023) / 1024;
    scan_a<<<nb, 256, 0, stream>>>(cnt, off, partial, N_ENT);
    scan_b<<<1, 256, 0, stream>>>(partial, nb);
    scan_c<<<(N_ENT + 255) / 256, 256, 0, stream>>>(off, cnt, partial, off, boff, bcur, N_ENT);
  }
  kgat_scatter1<<<(E + 255) / 256, 256, 0, stream>>>(edge_index, edge_type, bcur, stage, E);
  kgat_scatter2<<<NB, 256, 0, stream>>>(stage, off, boff, payload, N_ENT);
  {
    int blocks = (N_ENT * 16 + 255) / 256;
    kgat_aggr<<<blocks, 256, 0, stream>>>(off, payload, entity_emb, hdot, rb, out, N_ENT);
  }
  kgat_transform<<<2048, 256, 0, stream>>>(out, W_w, W_b, N_ENT);
}

// Round 7
// 312.947 us; speedup vs baseline: 1.3801x; 1.3801x over previous
//
#include <hip/hip_runtime.h>
#include <hip/hip_bf16.h>

// KGAT via on-device CSR (no float atomics):
//   k1 hdot:  hdot[n] = emb[n].att_w[0:64];  rb[r] = rel[r].att_w[64:128] + b
//   k2 hist:  cnt[head]++                      (int atomics)
//   k3 scan:  off = exclusive_scan(cnt)  (+ bucket offsets boff/bcur, off[N]=E)
//   k4 scatter1: bin edges by head>>6; bcur counters PADDED 1/cache-line
//      (16 counters/line caused ~10K serialized same-line atomics -> 173us)
//      packed 4B: (head&63)<<19 | rel<<18 | tail
//   k5 scatter2: block per bucket, LDS cursors -> exact CSR slot
//   k6 aggr+xform fused: per-head segment-sum, then in-register
//      tanh(acc @ W^T + b) (16 lanes/row, ILP=4, unroll 4, grid-stride
//      2048 blocks so W-staging amortizes) -> single final write.

#define DIM 64
#define TMASK 0x3FFFF
#define RBIT (1 << 18)

// ---------------- k1: per-entity attention dot ----------------
__global__ __launch_bounds__(256) void kgat_hdot(
    const float* __restrict__ emb, const float* __restrict__ rel,
    const float* __restrict__ att_w, const float* __restrict__ att_b,
    float* __restrict__ hdot, float* __restrict__ rb,
    int n_ent, int n_rel) {
  int gid = blockIdx.x * 256 + threadIdx.x;
  int n = gid >> 4;
  int q = threadIdx.x & 15;
  if (n >= n_ent + n_rel) return;
  float4 v, w;
  if (n < n_ent) {
    v = ((const float4*)emb)[n * 16 + q];
    w = ((const float4*)att_w)[q];
  } else {
    v = ((const float4*)rel)[(n - n_ent) * 16 + q];
    w = ((const float4*)att_w)[16 + q];
  }
  float p = v.x * w.x + v.y * w.y + v.z * w.z + v.w * w.w;
  p += __shfl_xor(p, 1);
  p += __shfl_xor(p, 2);
  p += __shfl_xor(p, 4);
  p += __shfl_xor(p, 8);
  if (q == 0) {
    if (n < n_ent) hdot[n] = p;
    else rb[n - n_ent] = p + att_b[0];
  }
}

// ---------------- k2: histogram of head degrees ----------------
__global__ __launch_bounds__(256) void kgat_hist(
    const int* __restrict__ ei, int* __restrict__ cnt, int E) {
  int e = blockIdx.x * 256 + threadIdx.x;
  if (e < E) atomicAdd(&cnt[ei[e]], 1);
}

// ---------------- k3: exclusive scan (1024 elems / block) ----------------
__global__ __launch_bounds__(256) void scan_a(
    const int* __restrict__ cnt, int* __restrict__ incl,
    int* __restrict__ partial, int n) {
  __shared__ int s[256];
  int base = blockIdx.x * 1024 + threadIdx.x * 4;
  int v0 = 0, v1 = 0, v2 = 0, v3 = 0;
  if (base + 0 < n) v0 = cnt[base + 0];
  if (base + 1 < n) v1 = cnt[base + 1];
  if (base + 2 < n) v2 = cnt[base + 2];
  if (base + 3 < n) v3 = cnt[base + 3];
  int tsum = v0 + v1 + v2 + v3;
  s[threadIdx.x] = tsum;
  __syncthreads();
  for (int d = 1; d < 256; d <<= 1) {
    int val = (threadIdx.x >= (unsigned)d) ? s[threadIdx.x - d] : 0;
    __syncthreads();
    s[threadIdx.x] += val;
    __syncthreads();
  }
  int texcl = s[threadIdx.x] - tsum;
  if (base + 0 < n) incl[base + 0] = texcl + v0;
  if (base + 1 < n) incl[base + 1] = texcl + v0 + v1;
  if (base + 2 < n) incl[base + 2] = texcl + v0 + v1 + v2;
  if (base + 3 < n) incl[base + 3] = texcl + tsum;
  if (threadIdx.x == 255) partial[blockIdx.x] = s[255];
}

__global__ __launch_bounds__(256) void scan_b(int* __restrict__ partial, int nb) {
  __shared__ int s[256];
  int v = (threadIdx.x < (unsigned)nb) ? partial[threadIdx.x] : 0;
  s[threadIdx.x] = v;
  __syncthreads();
  for (int d = 1; d < 256; d <<= 1) {
    int val = (threadIdx.x >= (unsigned)d) ? s[threadIdx.x - d] : 0;
    __syncthreads();
    s[threadIdx.x] += val;
    __syncthreads();
  }
  if (threadIdx.x < (unsigned)nb) partial[threadIdx.x] = s[threadIdx.x] - v;
}

__global__ __launch_bounds__(256) void scan_c(
    const int* __restrict__ incl, const int* __restrict__ cnt,
    const int* __restrict__ partial, int* __restrict__ off,
    int* __restrict__ boff, int* __restrict__ bcur, int n) {
  int i = blockIdx.x * 256 + threadIdx.x;
  if (i >= n) return;
  int c = cnt[i];
  int o = incl[i] - c + partial[i >> 10];
  off[i] = o;
  if ((i & 63) == 0) {
    boff[i >> 6] = o;
    bcur[(i >> 6) << 4] = o;   // padded: 1 counter per 64B line
  }
  if (i == n - 1) {
    off[n] = o + c;                 // = E
    boff[((n + 63) >> 6)] = o + c;  // sentinel bucket end
  }
}

// ---------------- k4: stage-1 binned scatter (bucket = head>>6) ----------------
__global__ __launch_bounds__(256) void kgat_scatter1(
    const int* __restrict__ ei, const int* __restrict__ et,
    int* __restrict__ bcur, int* __restrict__ stage, int E) {
  int e = blockIdx.x * 256 + threadIdx.x;
  if (e >= E) return;
  int h = ei[e];
  int t = ei[E + e];
  int r = et[e];
  int pos = atomicAdd(&bcur[(h >> 6) << 4], 1);  // padded counter
  stage[pos] = ((h & 63) << 19) | (r << 18) | t;
}

// ---------------- k5: stage-2 in-bucket placement (block per bucket) ----------------
__global__ __launch_bounds__(256) void kgat_scatter2(
    const int* __restrict__ stage, const int* __restrict__ off,
    const int* __restrict__ boff, int* __restrict__ payload, int n) {
  __shared__ int lcur[64];
  int b = blockIdx.x;
  int s0 = boff[b], s1 = boff[b + 1];
  if (threadIdx.x < 64) {
    int hidx = (b << 6) + threadIdx.x;
    lcur[threadIdx.x] = off[hidx < n ? hidx : n];
  }
  __syncthreads();
  for (int p = s0 + threadIdx.x; p < s1; p += 256) {
    int v = stage[p];
    int hl = (v >> 19) & 63;
    int pos = atomicAdd(&lcur[hl], 1);
    payload[pos] = v;
  }
}

// ---------------- k6: segment-sum + fused tanh(acc @ W^T + b) ----------------
__global__ __launch_bounds__(256) void kgat_aggr_fused(
    const int* __restrict__ off, const int* __restrict__ payload,
    const float* __restrict__ emb, const float* __restrict__ hdot,
    const float* __restrict__ rb, const float* __restrict__ Ww,
    const float* __restrict__ Wb, float* __restrict__ out, int n) {
  __shared__ float Ws[64][68];  // Ws[i][j] = Ww[j][i]
  for (int idx = threadIdx.x; idx < 64 * 64; idx += 256) {
    int j = idx >> 6, i = idx & 63;
    Ws[i][j] = Ww[idx];
  }
  __syncthreads();
  int q = threadIdx.x & 15;
  int grp = threadIdx.x >> 4;
  int lanebase = (threadIdx.x & 63) & ~15;
  int stride = gridDim.x * 16;
  float r0 = rb[0], r1 = rb[1];
  float4 bb = ((const float4*)Wb)[q];
  const float4* emb4 = (const float4*)emb;
  for (int h = blockIdx.x * 16 + grp; h < n; h += stride) {
    int p = off[h];
    int p1 = off[h + 1];
    float hd = hdot[h];
    float sc0 = 1.0f / (1.0f + __expf(-(hd + r0)));
    float sc1 = 1.0f / (1.0f + __expf(-(hd + r1)));
    float4 acc = make_float4(0.f, 0.f, 0.f, 0.f);
    for (; p + 4 <= p1; p += 4) {
      int v0 = payload[p + 0];
      int v1 = payload[p + 1];
      int v2 = payload[p + 2];
      int v3 = payload[p + 3];
      float4 t0 = emb4[(v0 & TMASK) * 16 + q];
      float4 t1 = emb4[(v1 & TMASK) * 16 + q];
      float4 t2 = emb4[(v2 & TMASK) * 16 + q];
      float4 t3 = emb4[(v3 & TMASK) * 16 + q];
      float s0 = (v0 & RBIT) ? sc1 : sc0;
      float s1 = (v1 & RBIT) ? sc1 : sc0;
      float s2 = (v2 & RBIT) ? sc1 : sc0;
      float s3 = (v3 & RBIT) ? sc1 : sc0;
      acc.x = fmaf(s0, t0.x, acc.x); acc.y = fmaf(s0, t0.y, acc.y);
      acc.z = fmaf(s0, t0.z, acc.z); acc.w = fmaf(s0, t0.w, acc.w);
      acc.x = fmaf(s1, t1.x, acc.x); acc.y = fmaf(s1, t1.y, acc.y);
      acc.z = fmaf(s1, t1.z, acc.z); acc.w = fmaf(s1, t1.w, acc.w);
      acc.x = fmaf(s2, t2.x, acc.x); acc.y = fmaf(s2, t2.y, acc.y);
      acc.z = fmaf(s2, t2.z, acc.z); acc.w = fmaf(s2, t2.w, acc.w);
      acc.x = fmaf(s3, t3.x, acc.x); acc.y = fmaf(s3, t3.y, acc.y);
      acc.z = fmaf(s3, t3.z, acc.z); acc.w = fmaf(s3, t3.w, acc.w);
    }
    for (; p < p1; ++p) {
      int v0 = payload[p];
      float s0 = (v0 & RBIT) ? sc1 : sc0;
      float4 t0 = emb4[(v0 & TMASK) * 16 + q];
      acc.x = fmaf(s0, t0.x, acc.x); acc.y = fmaf(s0, t0.y, acc.y);
      acc.z = fmaf(s0, t0.z, acc.z); acc.w = fmaf(s0, t0.w, acc.w);
    }
    // fused transform: o = tanh(W @ acc + b), acc distributed over 16 lanes
    float4 o = bb;
#pragma unroll 4
    for (int j = 0; j < 16; ++j) {
      float a0 = __shfl(acc.x, lanebase + j);
      float a1 = __shfl(acc.y, lanebase + j);
      float a2 = __shfl(acc.z, lanebase + j);
      float a3 = __shfl(acc.w, lanebase + j);
      float4 w0 = *(const float4*)&Ws[4 * j + 0][4 * q];
      float4 w1 = *(const float4*)&Ws[4 * j + 1][4 * q];
      float4 w2 = *(const float4*)&Ws[4 * j + 2][4 * q];
      float4 w3 = *(const float4*)&Ws[4 * j + 3][4 * q];
      o.x = fmaf(a0, w0.x, o.x); o.y = fmaf(a0, w0.y, o.y);
      o.z = fmaf(a0, w0.z, o.z); o.w = fmaf(a0, w0.w, o.w);
      o.x = fmaf(a1, w1.x, o.x); o.y = fmaf(a1, w1.y, o.y);
      o.z = fmaf(a1, w1.z, o.z); o.w = fmaf(a1, w1.w, o.w);
      o.x = fmaf(a2, w2.x, o.x); o.y = fmaf(a2, w2.y, o.y);
      o.z = fmaf(a2, w2.z, o.z); o.w = fmaf(a2, w2.w, o.w);
      o.x = fmaf(a3, w3.x, o.x); o.y = fmaf(a3, w3.y, o.y);
      o.z = fmaf(a3, w3.z, o.z); o.w = fmaf(a3, w3.w, o.w);
    }
    o.x = tanhf(o.x); o.y = tanhf(o.y); o.z = tanhf(o.z); o.w = tanhf(o.w);
    ((float4*)out)[h * 16 + q] = o;
  }
}

extern "C" void kernel_launch(void* const* d_in, const int* in_sizes, int n_in,
                              void* d_out, int out_size, void* d_ws, size_t ws_size,
                              hipStream_t stream) {
  const int* edge_index = (const int*)d_in[0];
  const int* edge_type  = (const int*)d_in[1];
  const float* entity_emb   = (const float*)d_in[2];
  const float* relation_emb = (const float*)d_in[3];
  const float* att_w = (const float*)d_in[4];
  const float* att_b = (const float*)d_in[5];
  const float* W_w   = (const float*)d_in[6];
  const float* W_b   = (const float*)d_in[7];
  float* out = (float*)d_out;

  const int E     = in_sizes[0] / 2;
  const int N_ENT = in_sizes[2] / DIM;
  const int N_REL = in_sizes[3] / DIM;
  const int NB    = (N_ENT + 63) >> 6;  // head buckets

  // ws layout (4B units)
  int* w32 = (int*)d_ws;
  float* hdot   = (float*)w32;                 // N_ENT
  float* rb     = (float*)(w32 + N_ENT);       // 8
  int*   cnt    = w32 + N_ENT + 8;             // N_ENT
  int*   off    = cnt + N_ENT;                 // N_ENT + 1
  int*   boff   = off + N_ENT + 1;             // NB + 1
  int*   bcur   = boff + NB + 1;               // NB * 16 (padded, 1/line)
  int*   partial= bcur + NB * 16;              // 256
  int*   stage  = partial + 256;               // E
  int*   payload= stage + E;                   // E

  hipMemsetAsync(cnt, 0, (size_t)N_ENT * sizeof(int), stream);

  {
    int blocks = ((N_ENT + N_REL) * 16 + 255) / 256;
    kgat_hdot<<<blocks, 256, 0, stream>>>(entity_emb, relation_emb, att_w, att_b,
                                          hdot, rb, N_ENT, N_REL);
  }
  kgat_hist<<<(E + 255) / 256, 256, 0, stream>>>(edge_index, cnt, E);
  {
    int nb = (N_ENT + 1023) / 1024;
    scan_a<<<nb, 256, 0, stream>>>(cnt, off, partial, N_ENT);
    scan_b<<<1, 256, 0, stream>>>(partial, nb);
    scan_c<<<(N_ENT + 255) / 256, 256, 0, stream>>>(off, cnt, partial, off, boff, bcur, N_ENT);
  }
  kgat_scatter1<<<(E + 255) / 256, 256, 0, stream>>>(edge_index, edge_type, bcur, stage, E);
  kgat_scatter2<<<NB, 256, 0, stream>>>(stage, off, boff, payload, N_ENT);
  kgat_aggr_fused<<<2048, 256, 0, stream>>>(off, payload, entity_emb, hdot, rb,
                                            W_w, W_b, out, N_ENT);
}